// Round 1
// baseline (367.568 us; speedup 1.0000x reference)
//
#include <hip/hip_runtime.h>
#include <stdint.h>

#define NROWS 8192
#define BHALF 4096
#define DIM 512

typedef __attribute__((ext_vector_type(8))) short bf16x8;
typedef __attribute__((ext_vector_type(4))) float f32x4;

__device__ __forceinline__ unsigned short f32_to_bf16(float f) {
  uint32_t u = __float_as_uint(f);
  u += 0x7fffu + ((u >> 16) & 1u);
  return (unsigned short)(u >> 16);
}
__device__ __forceinline__ float bf16_to_f32(unsigned short h) {
  return __uint_as_float(((uint32_t)h) << 16);
}

__device__ __forceinline__ void gload_lds16(const void* g, void* l) {
  __builtin_amdgcn_global_load_lds(
      (const __attribute__((address_space(1))) unsigned int*)g,
      (__attribute__((address_space(3))) unsigned int*)l, 16, 0, 0);
}

// ---------------- prep: norms, bf16 hi/lo split, trace ----------------
extern "C" __global__ __launch_bounds__(256) void k_prep(
    const float* __restrict__ za, const float* __restrict__ zp,
    unsigned short* __restrict__ zhi, unsigned short* __restrict__ zlo,
    float* __restrict__ inv_norms, float* __restrict__ trace_acc)
{
  __shared__ float tr_sh[4];
  const int wid = threadIdx.x >> 6, lane = threadIdx.x & 63;
  const int row = blockIdx.x * 4 + wid;
  const float* src = (row < BHALF) ? (za + (size_t)row * DIM)
                                   : (zp + (size_t)(row - BHALF) * DIM);
  const float4* s4 = (const float4*)src;
  float4 v0 = s4[lane * 2], v1 = s4[lane * 2 + 1];
  float x[8] = {v0.x, v0.y, v0.z, v0.w, v1.x, v1.y, v1.z, v1.w};
  float ss = 0.f;
#pragma unroll
  for (int j = 0; j < 8; ++j) ss += x[j] * x[j];
#pragma unroll
  for (int m = 1; m < 64; m <<= 1) ss += __shfl_xor(ss, m, 64);
  float norm = fmaxf(sqrtf(ss), 1e-8f);
  float tr = 0.f;
  unsigned short hi[8], lo[8];
#pragma unroll
  for (int j = 0; j < 8; ++j) {
    float zn = x[j] / norm;
    tr += zn * zn;
    hi[j] = f32_to_bf16(zn);
    lo[j] = f32_to_bf16(zn - bf16_to_f32(hi[j]));
  }
#pragma unroll
  for (int m = 1; m < 64; m <<= 1) tr += __shfl_xor(tr, m, 64);
  if (lane == 0) { tr_sh[wid] = tr; inv_norms[row] = 1.0f / norm; }
  uint32_t h01 = (uint32_t)hi[0] | ((uint32_t)hi[1] << 16);
  uint32_t h23 = (uint32_t)hi[2] | ((uint32_t)hi[3] << 16);
  uint32_t h45 = (uint32_t)hi[4] | ((uint32_t)hi[5] << 16);
  uint32_t h67 = (uint32_t)hi[6] | ((uint32_t)hi[7] << 16);
  uint32_t l01 = (uint32_t)lo[0] | ((uint32_t)lo[1] << 16);
  uint32_t l23 = (uint32_t)lo[2] | ((uint32_t)lo[3] << 16);
  uint32_t l45 = (uint32_t)lo[4] | ((uint32_t)lo[5] << 16);
  uint32_t l67 = (uint32_t)lo[6] | ((uint32_t)lo[7] << 16);
  uint4 hv = {h01, h23, h45, h67};
  uint4 lv = {l01, l23, l45, l67};
  ((uint4*)(zhi + (size_t)row * DIM))[lane] = hv;
  ((uint4*)(zlo + (size_t)row * DIM))[lane] = lv;
  __syncthreads();
  if (threadIdx.x == 0)
    atomicAdd(trace_acc, tr_sh[0] + tr_sh[1] + tr_sh[2] + tr_sh[3]);
}

// ---------------- column stats: colsum(z), colsumsq(z), colsum(zn) ----------------
extern "C" __global__ __launch_bounds__(256) void k_colstats(
    const float* __restrict__ za, const float* __restrict__ zp,
    const float* __restrict__ inv_norms,
    float* __restrict__ colsum, float* __restrict__ colsumsq,
    float* __restrict__ snorm)
{
  const int t = threadIdx.x;
  const int r0 = blockIdx.x * 64;
  float s0 = 0, q0 = 0, n0 = 0, s1 = 0, q1 = 0, n1 = 0;
  for (int rr = 0; rr < 64; ++rr) {
    int r = r0 + rr;
    const float* src = (r < BHALF) ? (za + (size_t)r * DIM)
                                   : (zp + (size_t)(r - BHALF) * DIM);
    float inv = inv_norms[r];
    float v0 = src[t], v1 = src[t + 256];
    s0 += v0; q0 += v0 * v0; n0 += v0 * inv;
    s1 += v1; q1 += v1 * v1; n1 += v1 * inv;
  }
  atomicAdd(&colsum[t], s0);       atomicAdd(&colsum[t + 256], s1);
  atomicAdd(&colsumsq[t], q0);     atomicAdd(&colsumsq[t + 256], q1);
  atomicAdd(&snorm[t], n0);        atomicAdd(&snorm[t + 256], n1);
}

// ---------------- pos_sim: per-pair normalized dot ----------------
extern "C" __global__ __launch_bounds__(256) void k_pos(
    const float* __restrict__ za, const float* __restrict__ zp,
    const float* __restrict__ inv_norms, float* __restrict__ posdot)
{
  __shared__ float sh[4];
  const int wid = threadIdx.x >> 6, lane = threadIdx.x & 63;
  const int i = blockIdx.x * 4 + wid;
  float ia = inv_norms[i], ip = inv_norms[i + BHALF];
  const float4* a4 = (const float4*)(za + (size_t)i * DIM);
  const float4* p4 = (const float4*)(zp + (size_t)i * DIM);
  float4 a0 = a4[lane * 2], a1 = a4[lane * 2 + 1];
  float4 p0 = p4[lane * 2], p1 = p4[lane * 2 + 1];
  float d = (a0.x * ia) * (p0.x * ip) + (a0.y * ia) * (p0.y * ip)
          + (a0.z * ia) * (p0.z * ip) + (a0.w * ia) * (p0.w * ip)
          + (a1.x * ia) * (p1.x * ip) + (a1.y * ia) * (p1.y * ip)
          + (a1.z * ia) * (p1.z * ip) + (a1.w * ia) * (p1.w * ip);
#pragma unroll
  for (int m = 1; m < 64; m <<= 1) d += __shfl_xor(d, m, 64);
  if (lane == 0) sh[wid] = d;
  __syncthreads();
  if (threadIdx.x == 0) atomicAdd(posdot, sh[0] + sh[1] + sh[2] + sh[3]);
}

// ---------------- main fused GEMM: split-bf16 cos + row sumexp/argmax ----------------
extern "C" __global__ __launch_bounds__(256) void k_gemm(
    const unsigned short* __restrict__ zhi, const unsigned short* __restrict__ zlo,
    float* __restrict__ sumexp, unsigned long long* __restrict__ amax)
{
  __shared__ unsigned short lds[4 * 4096];  // Ahi|Alo|Bhi|Blo, each [128][32] bf16 (8KB)
  const int tid = threadIdx.x;
  const int wid = tid >> 6, lane = tid & 63;
  const int wr = wid >> 1, wc = wid & 1;
  const int bi = blockIdx.x >> 6, bj = blockIdx.x & 63;
  const int rowA = bi * 128, rowB = bj * 128;

  f32x4 acc[4][4];
#pragma unroll
  for (int m = 0; m < 4; ++m)
#pragma unroll
    for (int n = 0; n < 4; ++n) acc[m][n] = (f32x4){0.f, 0.f, 0.f, 0.f};

  const unsigned short* srcs[4] = {
      zhi + (size_t)rowA * DIM, zlo + (size_t)rowA * DIM,
      zhi + (size_t)rowB * DIM, zlo + (size_t)rowB * DIM};

  const int fr = lane & 15, koff = (lane >> 4) * 8;

  for (int kt = 0; kt < 16; ++kt) {
    if (kt) __syncthreads();
    // stage 4 tiles via global_load_lds (linear LDS dest, pre-swizzled global src)
#pragma unroll
    for (int tI = 0; tI < 4; ++tI) {
#pragma unroll
      for (int s = 0; s < 2; ++s) {
        int chunk = (wid * 2 + s) * 1024;             // wave-uniform 1KB chunk
        int off = chunk + lane * 16;                  // physical byte in tile
        int loff = off ^ (((off >> 7) & 3) << 4);     // logical byte (involution)
        int r = loff >> 6, cb = loff & 63;
        const unsigned short* g = srcs[tI] + (size_t)r * DIM + kt * 32 + (cb >> 1);
        gload_lds16(g, (char*)lds + tI * 8192 + chunk);
      }
    }
    __syncthreads();

    bf16x8 ah[4], al[4], bh[4], bl[4];
#pragma unroll
    for (int m = 0; m < 4; ++m) {
      int r = wr * 64 + m * 16 + fr;
      int pb = (r * 64 + koff * 2) ^ (((r >> 1) & 3) << 4);
      ah[m] = *(const bf16x8*)((const char*)lds + 0 * 8192 + pb);
      al[m] = *(const bf16x8*)((const char*)lds + 1 * 8192 + pb);
    }
#pragma unroll
    for (int n = 0; n < 4; ++n) {
      int r = wc * 64 + n * 16 + fr;
      int pb = (r * 64 + koff * 2) ^ (((r >> 1) & 3) << 4);
      bh[n] = *(const bf16x8*)((const char*)lds + 2 * 8192 + pb);
      bl[n] = *(const bf16x8*)((const char*)lds + 3 * 8192 + pb);
    }
#pragma unroll
    for (int m = 0; m < 4; ++m)
#pragma unroll
      for (int n = 0; n < 4; ++n) {
        acc[m][n] = __builtin_amdgcn_mfma_f32_16x16x32_bf16(ah[m], bh[n], acc[m][n], 0, 0, 0);
        acc[m][n] = __builtin_amdgcn_mfma_f32_16x16x32_bf16(ah[m], bl[n], acc[m][n], 0, 0, 0);
        acc[m][n] = __builtin_amdgcn_mfma_f32_16x16x32_bf16(al[m], bh[n], acc[m][n], 0, 0, 0);
      }
  }

  // epilogue: per-row exp-sum + packed max/argmax, reduce across 16 col-lanes
  const int fq = lane >> 4;
#pragma unroll
  for (int m = 0; m < 4; ++m) {
#pragma unroll
    for (int rr = 0; rr < 4; ++rr) {
      int gi = rowA + wr * 64 + m * 16 + fq * 4 + rr;
      float se = 0.f;
      unsigned long long best = 0ull;
#pragma unroll
      for (int n = 0; n < 4; ++n) {
        int gj = rowB + wc * 64 + n * 16 + fr;
        if (gi != gj) {
          float logit = 2.0f * acc[m][n][rr];   // /T with T=0.5
          se += __expf(logit);
          uint32_t bu = __float_as_uint(logit);
          uint32_t s = (bu & 0x80000000u) ? ~bu : (bu | 0x80000000u);
          unsigned long long p =
              ((unsigned long long)s << 32) | (uint32_t)(~(uint32_t)gj);
          if (p > best) best = p;
        }
      }
#pragma unroll
      for (int msk = 1; msk < 16; msk <<= 1) {
        se += __shfl_xor(se, msk, 64);
        unsigned long long o = __shfl_xor(best, msk, 64);
        if (o > best) best = o;
      }
      if (fr == 0) {
        atomicAdd(&sumexp[gi], se);
        atomicMax(&amax[gi], best);
      }
    }
  }
}

// ---------------- final combine ----------------
extern "C" __global__ __launch_bounds__(256) void k_final(
    const float* __restrict__ sumexp, const unsigned long long* __restrict__ amax,
    const float* __restrict__ colsum, const float* __restrict__ colsumsq,
    const float* __restrict__ snorm, const float* __restrict__ scalars,
    float* __restrict__ out)
{
  __shared__ double red[256];
  const int t = threadIdx.x;
  double lsesum = 0.0, cnt = 0.0;
  for (int r = t; r < NROWS; r += 256) {
    lsesum += log((double)sumexp[r]);
    int label = (r < BHALF) ? r + BHALF : r - BHALF;
    unsigned int idx = ~(unsigned int)(amax[r] & 0xffffffffull);
    if ((int)idx == label) cnt += 1.0;
  }
  double stdsum = 0, mn2 = 0, sn2 = 0;
  for (int c = t; c < DIM; c += 256) {
    double su = colsum[c], sq = colsumsq[c];
    double var = (sq - su * su / 8192.0) / 8191.0;
    stdsum += sqrt(var > 0.0 ? var : 0.0);
    double m = su / 8192.0; mn2 += m * m;
    double s = snorm[c];   sn2 += s * s;
  }
  auto red_sum = [&](double v) -> double {
    __syncthreads();
    red[t] = v; __syncthreads();
    for (int s = 128; s > 0; s >>= 1) {
      if (t < s) red[t] += red[t + s];
      __syncthreads();
    }
    return red[0];
  };
  double Tlse = red_sum(lsesum);
  double Tcnt = red_sum(cnt);
  double Tstd = red_sum(stdsum);
  double Tmn2 = red_sum(mn2);
  double Tsn2 = red_sum(sn2);
  if (t == 0) {
    double trace = scalars[0], posdot = scalars[1];
    double pos_sim = posdot / 4096.0;
    out[0] = (float)(Tlse / 8192.0 - 2.0 * pos_sim);       // loss (mean lse - mean pos_logit)
    out[1] = (float)(Tcnt / 8192.0);                        // accuracy
    out[2] = (float)pos_sim;                                // pos_sim
    out[3] = (float)((Tsn2 - trace) / (8192.0 * 8191.0));   // neg_sim via ||sum zn||^2
    out[4] = (float)(Tstd / 512.0);                         // z_std
    out[5] = (float)sqrt(Tmn2);                             // z_mean_norm
  }
}

extern "C" void kernel_launch(void* const* d_in, const int* in_sizes, int n_in,
                              void* d_out, int out_size, void* d_ws, size_t ws_size,
                              hipStream_t stream) {
  const float* za = (const float*)d_in[0];
  const float* zp = (const float*)d_in[1];
  float* out = (float*)d_out;
  char* ws = (char*)d_ws;
  size_t off = 0;
  unsigned short* zhi = (unsigned short*)(ws + off); off += (size_t)NROWS * DIM * 2;
  unsigned short* zlo = (unsigned short*)(ws + off); off += (size_t)NROWS * DIM * 2;
  float* inv_norms = (float*)(ws + off); off += (size_t)NROWS * 4;
  char* zbase = ws + off;
  float* sumexp = (float*)(ws + off); off += (size_t)NROWS * 4;
  unsigned long long* amax = (unsigned long long*)(ws + off); off += (size_t)NROWS * 8;
  float* colsum = (float*)(ws + off); off += (size_t)DIM * 4;
  float* colsumsq = (float*)(ws + off); off += (size_t)DIM * 4;
  float* snorm = (float*)(ws + off); off += (size_t)DIM * 4;
  float* scalars = (float*)(ws + off); off += 64;
  size_t zsize = (size_t)((ws + off) - zbase);

  hipMemsetAsync(zbase, 0, zsize, stream);
  k_prep<<<dim3(2048), dim3(256), 0, stream>>>(za, zp, zhi, zlo, inv_norms, scalars + 0);
  k_colstats<<<dim3(128), dim3(256), 0, stream>>>(za, zp, inv_norms, colsum, colsumsq, snorm);
  k_pos<<<dim3(1024), dim3(256), 0, stream>>>(za, zp, inv_norms, scalars + 1);
  k_gemm<<<dim3(4096), dim3(256), 0, stream>>>(zhi, zlo, sumexp, amax);
  k_final<<<dim3(1), dim3(256), 0, stream>>>(sumexp, amax, colsum, colsumsq, snorm, scalars, out);
}

// Round 2
// 255.250 us; speedup vs baseline: 1.4400x; 1.4400x over previous
//
#include <hip/hip_runtime.h>
#include <stdint.h>

#define NROWS 8192
#define BHALF 4096
#define DIM 512
#define NBLK 64            // 8192/128 row-blocks
#define NTRI 2080          // 64*65/2 upper-triangle blocks

typedef __attribute__((ext_vector_type(8))) short bf16x8;
typedef __attribute__((ext_vector_type(4))) float f32x4;

__device__ __forceinline__ unsigned short f32_to_bf16(float f) {
  uint32_t u = __float_as_uint(f);
  u += 0x7fffu + ((u >> 16) & 1u);
  return (unsigned short)(u >> 16);
}
__device__ __forceinline__ float bf16_to_f32(unsigned short h) {
  return __uint_as_float(((uint32_t)h) << 16);
}

__device__ __forceinline__ void gload_lds16(const void* g, void* l) {
  __builtin_amdgcn_global_load_lds(
      (const __attribute__((address_space(1))) unsigned int*)g,
      (__attribute__((address_space(3))) unsigned int*)l, 16, 0, 0);
}

// ---------------- fused prep: norms, bf16 hi/lo split, trace, pos_sim ----------------
// One wave per (anchor,positive) pair: reads both rows once, emits both bf16 rows.
extern "C" __global__ __launch_bounds__(256) void k_prep(
    const float* __restrict__ za, const float* __restrict__ zp,
    unsigned short* __restrict__ zhi, unsigned short* __restrict__ zlo,
    float* __restrict__ inv_norms, float* __restrict__ scalars)
{
  __shared__ float tr_sh[4], pd_sh[4];
  const int wid = threadIdx.x >> 6, lane = threadIdx.x & 63;
  const int i = blockIdx.x * 4 + wid;                 // pair index in [0,4096)
  const float4* a4 = (const float4*)(za + (size_t)i * DIM);
  const float4* p4 = (const float4*)(zp + (size_t)i * DIM);
  float4 a0 = a4[lane * 2], a1 = a4[lane * 2 + 1];
  float4 p0 = p4[lane * 2], p1 = p4[lane * 2 + 1];
  float xa[8] = {a0.x, a0.y, a0.z, a0.w, a1.x, a1.y, a1.z, a1.w};
  float xp[8] = {p0.x, p0.y, p0.z, p0.w, p1.x, p1.y, p1.z, p1.w};
  float ssa = 0.f, ssp = 0.f;
#pragma unroll
  for (int j = 0; j < 8; ++j) { ssa += xa[j] * xa[j]; ssp += xp[j] * xp[j]; }
#pragma unroll
  for (int m = 1; m < 64; m <<= 1) {
    ssa += __shfl_xor(ssa, m, 64);
    ssp += __shfl_xor(ssp, m, 64);
  }
  float na = fmaxf(sqrtf(ssa), 1e-8f), np_ = fmaxf(sqrtf(ssp), 1e-8f);
  float ia = 1.0f / na, ip = 1.0f / np_;
  float pd = 0.f;
  unsigned short ha[8], la[8], hp[8], lp[8];
#pragma unroll
  for (int j = 0; j < 8; ++j) {
    float zna = xa[j] * ia, znp = xp[j] * ip;
    pd += zna * znp;
    ha[j] = f32_to_bf16(zna); la[j] = f32_to_bf16(zna - bf16_to_f32(ha[j]));
    hp[j] = f32_to_bf16(znp); lp[j] = f32_to_bf16(znp - bf16_to_f32(hp[j]));
  }
#pragma unroll
  for (int m = 1; m < 64; m <<= 1) pd += __shfl_xor(pd, m, 64);
  float tr = ssa * ia * ia + ssp * ip * ip;           // ||zn_a||^2 + ||zn_p||^2
  if (lane == 0) {
    tr_sh[wid] = tr; pd_sh[wid] = pd;
    inv_norms[i] = ia; inv_norms[i + BHALF] = ip;
  }
  uint4 hva = {(uint32_t)ha[0] | ((uint32_t)ha[1] << 16), (uint32_t)ha[2] | ((uint32_t)ha[3] << 16),
               (uint32_t)ha[4] | ((uint32_t)ha[5] << 16), (uint32_t)ha[6] | ((uint32_t)ha[7] << 16)};
  uint4 lva = {(uint32_t)la[0] | ((uint32_t)la[1] << 16), (uint32_t)la[2] | ((uint32_t)la[3] << 16),
               (uint32_t)la[4] | ((uint32_t)la[5] << 16), (uint32_t)la[6] | ((uint32_t)la[7] << 16)};
  uint4 hvp = {(uint32_t)hp[0] | ((uint32_t)hp[1] << 16), (uint32_t)hp[2] | ((uint32_t)hp[3] << 16),
               (uint32_t)hp[4] | ((uint32_t)hp[5] << 16), (uint32_t)hp[6] | ((uint32_t)hp[7] << 16)};
  uint4 lvp = {(uint32_t)lp[0] | ((uint32_t)lp[1] << 16), (uint32_t)lp[2] | ((uint32_t)lp[3] << 16),
               (uint32_t)lp[4] | ((uint32_t)lp[5] << 16), (uint32_t)lp[6] | ((uint32_t)lp[7] << 16)};
  ((uint4*)(zhi + (size_t)i * DIM))[lane] = hva;
  ((uint4*)(zlo + (size_t)i * DIM))[lane] = lva;
  ((uint4*)(zhi + (size_t)(i + BHALF) * DIM))[lane] = hvp;
  ((uint4*)(zlo + (size_t)(i + BHALF) * DIM))[lane] = lvp;
  __syncthreads();
  if (threadIdx.x == 0) {
    atomicAdd(&scalars[0], tr_sh[0] + tr_sh[1] + tr_sh[2] + tr_sh[3]);
    atomicAdd(&scalars[1], pd_sh[0] + pd_sh[1] + pd_sh[2] + pd_sh[3]);
  }
}

// ---------------- column stats: colsum(z), colsumsq(z), colsum(zn) ----------------
extern "C" __global__ __launch_bounds__(256) void k_colstats(
    const float* __restrict__ za, const float* __restrict__ zp,
    const float* __restrict__ inv_norms,
    float* __restrict__ colsum, float* __restrict__ colsumsq,
    float* __restrict__ snorm)
{
  const int t = threadIdx.x;
  const int r0 = blockIdx.x * 64;
  float s0 = 0, q0 = 0, n0 = 0, s1 = 0, q1 = 0, n1 = 0;
  for (int rr = 0; rr < 64; ++rr) {
    int r = r0 + rr;
    const float* src = (r < BHALF) ? (za + (size_t)r * DIM)
                                   : (zp + (size_t)(r - BHALF) * DIM);
    float inv = inv_norms[r];
    float v0 = src[t], v1 = src[t + 256];
    s0 += v0; q0 += v0 * v0; n0 += v0 * inv;
    s1 += v1; q1 += v1 * v1; n1 += v1 * inv;
  }
  atomicAdd(&colsum[t], s0);       atomicAdd(&colsum[t + 256], s1);
  atomicAdd(&colsumsq[t], q0);     atomicAdd(&colsumsq[t + 256], q1);
  atomicAdd(&snorm[t], n0);        atomicAdd(&snorm[t + 256], n1);
}

// ---------------- main fused GEMM: split-bf16 cos + row sumexp/argmax ----------------
// Symmetric: only upper-triangle blocks (bi<=bj). Off-diagonal blocks emit both
// the row-side (rows of A-panel) and column-side (rows of B-panel, via cos^T=cos)
// reductions.
extern "C" __global__ __launch_bounds__(256) void k_gemm(
    const unsigned short* __restrict__ zhi, const unsigned short* __restrict__ zlo,
    float* __restrict__ sumexp, unsigned long long* __restrict__ amax)
{
  __shared__ unsigned short lds[4 * 4096];  // Ahi|Alo|Bhi|Blo, each [128][32] bf16 (8KB)
  const int tid = threadIdx.x;
  const int wid = tid >> 6, lane = tid & 63;
  const int wr = wid >> 1, wc = wid & 1;

  // triangular decode: blockIdx.x -> (bi, bj) with bi <= bj
  int t = blockIdx.x;
  int bi = (int)(64.5f - sqrtf(64.5f * 64.5f - 2.0f * (float)t));
  if (bi < 0) bi = 0; if (bi > 63) bi = 63;
  while (bi > 0 && (bi * NBLK - bi * (bi - 1) / 2) > t) --bi;
  while (bi < 63 && ((bi + 1) * NBLK - (bi + 1) * bi / 2) <= t) ++bi;
  const int bj = bi + (t - (bi * NBLK - bi * (bi - 1) / 2));
  const int rowA = bi * 128, rowB = bj * 128;

  f32x4 acc[4][4];
#pragma unroll
  for (int m = 0; m < 4; ++m)
#pragma unroll
    for (int n = 0; n < 4; ++n) acc[m][n] = (f32x4){0.f, 0.f, 0.f, 0.f};

  const unsigned short* srcs[4] = {
      zhi + (size_t)rowA * DIM, zlo + (size_t)rowA * DIM,
      zhi + (size_t)rowB * DIM, zlo + (size_t)rowB * DIM};

  const int fr = lane & 15, koff = (lane >> 4) * 8;

  for (int kt = 0; kt < 16; ++kt) {
    if (kt) __syncthreads();
    // stage 4 tiles via global_load_lds (linear LDS dest, pre-swizzled global src)
#pragma unroll
    for (int tI = 0; tI < 4; ++tI) {
#pragma unroll
      for (int s = 0; s < 2; ++s) {
        int chunk = (wid * 2 + s) * 1024;             // wave-uniform 1KB chunk
        int off = chunk + lane * 16;                  // physical byte in tile
        int loff = off ^ (((off >> 7) & 3) << 4);     // logical byte (involution)
        int r = loff >> 6, cb = loff & 63;
        const unsigned short* g = srcs[tI] + (size_t)r * DIM + kt * 32 + (cb >> 1);
        gload_lds16(g, (char*)lds + tI * 8192 + chunk);
      }
    }
    __syncthreads();

    bf16x8 ah[4], al[4], bh[4], bl[4];
#pragma unroll
    for (int m = 0; m < 4; ++m) {
      int r = wr * 64 + m * 16 + fr;
      int pb = (r * 64 + koff * 2) ^ (((r >> 1) & 3) << 4);
      ah[m] = *(const bf16x8*)((const char*)lds + 0 * 8192 + pb);
      al[m] = *(const bf16x8*)((const char*)lds + 1 * 8192 + pb);
    }
#pragma unroll
    for (int n = 0; n < 4; ++n) {
      int r = wc * 64 + n * 16 + fr;
      int pb = (r * 64 + koff * 2) ^ (((r >> 1) & 3) << 4);
      bh[n] = *(const bf16x8*)((const char*)lds + 2 * 8192 + pb);
      bl[n] = *(const bf16x8*)((const char*)lds + 3 * 8192 + pb);
    }
#pragma unroll
    for (int m = 0; m < 4; ++m)
#pragma unroll
      for (int n = 0; n < 4; ++n) {
        acc[m][n] = __builtin_amdgcn_mfma_f32_16x16x32_bf16(ah[m], bh[n], acc[m][n], 0, 0, 0);
        acc[m][n] = __builtin_amdgcn_mfma_f32_16x16x32_bf16(ah[m], bl[n], acc[m][n], 0, 0, 0);
        acc[m][n] = __builtin_amdgcn_mfma_f32_16x16x32_bf16(al[m], bh[n], acc[m][n], 0, 0, 0);
      }
  }

  const int fq = lane >> 4;

  // row-side epilogue: rows gi (A-panel), reduce across the 16 col-lanes (fr)
#pragma unroll
  for (int m = 0; m < 4; ++m) {
#pragma unroll
    for (int rr = 0; rr < 4; ++rr) {
      int gi = rowA + wr * 64 + m * 16 + fq * 4 + rr;
      float se = 0.f;
      unsigned long long best = 0ull;
#pragma unroll
      for (int n = 0; n < 4; ++n) {
        int gj = rowB + wc * 64 + n * 16 + fr;
        if (gi != gj) {
          float logit = 2.0f * acc[m][n][rr];   // /T with T=0.5
          se += __expf(logit);
          uint32_t bu = __float_as_uint(logit);
          uint32_t s = (bu & 0x80000000u) ? ~bu : (bu | 0x80000000u);
          unsigned long long p =
              ((unsigned long long)s << 32) | (uint32_t)(~(uint32_t)gj);
          if (p > best) best = p;
        }
      }
#pragma unroll
      for (int msk = 1; msk < 16; msk <<= 1) {
        se += __shfl_xor(se, msk, 64);
        unsigned long long o = __shfl_xor(best, msk, 64);
        if (o > best) best = o;
      }
      if (fr == 0) {
        atomicAdd(&sumexp[gi], se);
        atomicMax(&amax[gi], best);
      }
    }
  }

  // column-side epilogue (off-diagonal only): rows gj (B-panel), using
  // cos[j][i] == cos[i][j]; reduce along m/fq/rr (shfl masks 16,32).
  if (bi != bj) {
#pragma unroll
    for (int n = 0; n < 4; ++n) {
      int gj = rowB + wc * 64 + n * 16 + fr;
      float se = 0.f;
      unsigned long long best = 0ull;
#pragma unroll
      for (int m = 0; m < 4; ++m) {
#pragma unroll
        for (int rr = 0; rr < 4; ++rr) {
          int gi = rowA + wr * 64 + m * 16 + fq * 4 + rr;
          float logit = 2.0f * acc[m][n][rr];
          se += __expf(logit);
          uint32_t bu = __float_as_uint(logit);
          uint32_t s = (bu & 0x80000000u) ? ~bu : (bu | 0x80000000u);
          unsigned long long p =
              ((unsigned long long)s << 32) | (uint32_t)(~(uint32_t)gi);
          if (p > best) best = p;
        }
      }
#pragma unroll
      for (int msk = 16; msk < 64; msk <<= 1) {
        se += __shfl_xor(se, msk, 64);
        unsigned long long o = __shfl_xor(best, msk, 64);
        if (o > best) best = o;
      }
      if (fq == 0) {
        atomicAdd(&sumexp[gj], se);
        atomicMax(&amax[gj], best);
      }
    }
  }
}

// ---------------- final combine ----------------
extern "C" __global__ __launch_bounds__(1024) void k_final(
    const float* __restrict__ sumexp, const unsigned long long* __restrict__ amax,
    const float* __restrict__ colsum, const float* __restrict__ colsumsq,
    const float* __restrict__ snorm, const float* __restrict__ scalars,
    float* __restrict__ out)
{
  __shared__ double red[1024];
  const int t = threadIdx.x;
  double lsesum = 0.0, cnt = 0.0;
  for (int r = t; r < NROWS; r += 1024) {
    lsesum += log((double)sumexp[r]);
    int label = (r < BHALF) ? r + BHALF : r - BHALF;
    unsigned int idx = ~(unsigned int)(amax[r] & 0xffffffffull);
    if ((int)idx == label) cnt += 1.0;
  }
  double stdsum = 0, mn2 = 0, sn2 = 0;
  for (int c = t; c < DIM; c += 1024) {
    double su = colsum[c], sq = colsumsq[c];
    double var = (sq - su * su / 8192.0) / 8191.0;
    stdsum += sqrt(var > 0.0 ? var : 0.0);
    double m = su / 8192.0; mn2 += m * m;
    double s = snorm[c];   sn2 += s * s;
  }
  auto red_sum = [&](double v) -> double {
    __syncthreads();
    red[t] = v; __syncthreads();
    for (int s = 512; s > 0; s >>= 1) {
      if (t < s) red[t] += red[t + s];
      __syncthreads();
    }
    return red[0];
  };
  double Tlse = red_sum(lsesum);
  double Tcnt = red_sum(cnt);
  double Tstd = red_sum(stdsum);
  double Tmn2 = red_sum(mn2);
  double Tsn2 = red_sum(sn2);
  if (t == 0) {
    double trace = scalars[0], posdot = scalars[1];
    double pos_sim = posdot / 4096.0;
    out[0] = (float)(Tlse / 8192.0 - 2.0 * pos_sim);       // loss (mean lse - mean pos_logit)
    out[1] = (float)(Tcnt / 8192.0);                        // accuracy
    out[2] = (float)pos_sim;                                // pos_sim
    out[3] = (float)((Tsn2 - trace) / (8192.0 * 8191.0));   // neg_sim via ||sum zn||^2
    out[4] = (float)(Tstd / 512.0);                         // z_std
    out[5] = (float)sqrt(Tmn2);                             // z_mean_norm
  }
}

extern "C" void kernel_launch(void* const* d_in, const int* in_sizes, int n_in,
                              void* d_out, int out_size, void* d_ws, size_t ws_size,
                              hipStream_t stream) {
  const float* za = (const float*)d_in[0];
  const float* zp = (const float*)d_in[1];
  float* out = (float*)d_out;
  char* ws = (char*)d_ws;
  size_t off = 0;
  unsigned short* zhi = (unsigned short*)(ws + off); off += (size_t)NROWS * DIM * 2;
  unsigned short* zlo = (unsigned short*)(ws + off); off += (size_t)NROWS * DIM * 2;
  float* inv_norms = (float*)(ws + off); off += (size_t)NROWS * 4;
  char* zbase = ws + off;
  float* sumexp = (float*)(ws + off); off += (size_t)NROWS * 4;
  unsigned long long* amax = (unsigned long long*)(ws + off); off += (size_t)NROWS * 8;
  float* colsum = (float*)(ws + off); off += (size_t)DIM * 4;
  float* colsumsq = (float*)(ws + off); off += (size_t)DIM * 4;
  float* snorm = (float*)(ws + off); off += (size_t)DIM * 4;
  float* scalars = (float*)(ws + off); off += 64;
  size_t zsize = (size_t)((ws + off) - zbase);

  hipMemsetAsync(zbase, 0, zsize, stream);
  k_prep<<<dim3(1024), dim3(256), 0, stream>>>(za, zp, zhi, zlo, inv_norms, scalars);
  k_colstats<<<dim3(128), dim3(256), 0, stream>>>(za, zp, inv_norms, colsum, colsumsq, snorm);
  k_gemm<<<dim3(NTRI), dim3(256), 0, stream>>>(zhi, zlo, sumexp, amax);
  k_final<<<dim3(1), dim3(1024), 0, stream>>>(sumexp, amax, colsum, colsumsq, snorm, scalars, out);
}